// Round 1
// baseline (446.475 us; speedup 1.0000x reference)
//
#include <hip/hip_runtime.h>
#include <cstdint>
#include <cstddef>

typedef __bf16 bf16x8 __attribute__((ext_vector_type(8)));
typedef float f32x4 __attribute__((ext_vector_type(4)));
typedef unsigned short u16;
typedef unsigned int u32;

static constexpr int T = 2048;
static constexpr int DM = 1024;
static constexpr int DH = 64;

__device__ __forceinline__ u16 f2bf(float f) {
  u32 u = __builtin_bit_cast(u32, f);
  u += 0x7fffu + ((u >> 16) & 1u);
  return (u16)(u >> 16);
}

union U128 { uint4 u; bf16x8 b; u16 s[8]; };

// ---------------- Weight transpose + convert: Wt[n][k] bf16 from W[k][n] fp32 --------
__global__ __launch_bounds__(256) void wt_kernel(
    const float* __restrict__ W0, const float* __restrict__ W1, const float* __restrict__ W2,
    u16* __restrict__ O0, u16* __restrict__ O1, u16* __restrict__ O2) {
  const float* W = blockIdx.z == 0 ? W0 : blockIdx.z == 1 ? W1 : W2;
  u16* O = blockIdx.z == 0 ? O0 : blockIdx.z == 1 ? O1 : O2;
  const int k0 = blockIdx.x * 64, n0 = blockIdx.y * 64;
  __shared__ float tile[64][68];  // 68*4=272B stride, 16B aligned
  const int tid = threadIdx.x;
#pragma unroll
  for (int it = 0; it < 4; ++it) {
    int chunk = tid + it * 256;          // 1024 float4 chunks
    int r = chunk >> 4, c4 = (chunk & 15) * 4;
    *(float4*)&tile[r][c4] = *(const float4*)(W + (size_t)(k0 + r) * DM + n0 + c4);
  }
  __syncthreads();
#pragma unroll
  for (int it = 0; it < 4; ++it) {
    int chunk = tid + it * 256;
    int n = chunk >> 4, k4 = (chunk & 15) * 4;
    ushort4 o;
    o.x = f2bf(tile[k4 + 0][n]);
    o.y = f2bf(tile[k4 + 1][n]);
    o.z = f2bf(tile[k4 + 2][n]);
    o.w = f2bf(tile[k4 + 3][n]);
    *(ushort4*)(O + (size_t)(n0 + n) * DM + k0 + k4) = o;
  }
}

// ---------------- Projection GEMM: O[M,N] bf16 = X[M,K] fp32 * Wt^T, 128x128 tile ----
__global__ __launch_bounds__(256) void gemm_proj(
    const float* __restrict__ Xq, const float* __restrict__ Xk, const float* __restrict__ Xv,
    const u16* __restrict__ Wq, const u16* __restrict__ Wk, const u16* __restrict__ Wv,
    u16* __restrict__ Oq, u16* __restrict__ Ok, u16* __restrict__ Ov) {
  const int z = blockIdx.z;
  const float* X = z == 0 ? Xq : z == 1 ? Xk : Xv;
  const u16* Wt = z == 0 ? Wq : z == 1 ? Wk : Wv;   // [N][K] bf16
  u16* O = z == 0 ? Oq : z == 1 ? Ok : Ov;
  const int m0 = blockIdx.x * 128, n0 = blockIdx.y * 128;
  __shared__ u16 Al[128][40];   // stride 80B (16B aligned), breaks pow2 banks
  __shared__ u16 Bl[128][40];
  const int tid = threadIdx.x, wave = tid >> 6, lane = tid & 63;
  const int c16 = lane & 15, quad = lane >> 4;
  const int wm = (wave >> 1) * 64, wn = (wave & 1) * 64;
  f32x4 acc[4][4] = {};
  for (int kk = 0; kk < 1024; kk += 32) {
    __syncthreads();
#pragma unroll
    for (int it = 0; it < 2; ++it) {
      int chunk = tid + it * 256;       // 512 chunks of 8 elems
      int r = chunk >> 2, c8 = (chunk & 3) * 8;
      const float* ap = X + (size_t)(m0 + r) * DM + kk + c8;
      float4 a0 = *(const float4*)ap, a1 = *(const float4*)(ap + 4);
      U128 pk;
      pk.s[0] = f2bf(a0.x); pk.s[1] = f2bf(a0.y); pk.s[2] = f2bf(a0.z); pk.s[3] = f2bf(a0.w);
      pk.s[4] = f2bf(a1.x); pk.s[5] = f2bf(a1.y); pk.s[6] = f2bf(a1.z); pk.s[7] = f2bf(a1.w);
      *(uint4*)&Al[r][c8] = pk.u;
      *(uint4*)&Bl[r][c8] = *(const uint4*)(Wt + (size_t)(n0 + r) * DM + kk + c8);
    }
    __syncthreads();
    bf16x8 af[4], bfr[4];
#pragma unroll
    for (int t = 0; t < 4; ++t) af[t] = *(const bf16x8*)&Al[wm + t * 16 + c16][quad * 8];
#pragma unroll
    for (int t = 0; t < 4; ++t) bfr[t] = *(const bf16x8*)&Bl[wn + t * 16 + c16][quad * 8];
#pragma unroll
    for (int mt = 0; mt < 4; ++mt)
#pragma unroll
      for (int nt = 0; nt < 4; ++nt)
        acc[mt][nt] = __builtin_amdgcn_mfma_f32_16x16x32_bf16(af[mt], bfr[nt], acc[mt][nt], 0, 0, 0);
  }
#pragma unroll
  for (int mt = 0; mt < 4; ++mt)
#pragma unroll
    for (int nt = 0; nt < 4; ++nt)
#pragma unroll
      for (int r = 0; r < 4; ++r) {
        size_t row = m0 + wm + mt * 16 + quad * 4 + r;
        size_t col = n0 + wn + nt * 16 + c16;
        O[row * DM + col] = f2bf(acc[mt][nt][r]);
      }
}

// ---------------- VH transpose: VHt[bh][d][t] = VH[b][t][h*64+d] ----------------------
__global__ __launch_bounds__(256) void vt_kernel(const u16* __restrict__ VH, u16* __restrict__ VHt) {
  const int tt = blockIdx.x & 31, bh = blockIdx.x >> 5;
  const int b = bh >> 4, h = bh & 15;
  __shared__ u16 tile[64][80];
  const int tid = threadIdx.x;
#pragma unroll
  for (int it = 0; it < 2; ++it) {
    int chunk = tid + it * 256;
    int t = chunk >> 3, c8 = (chunk & 7) * 8;
    *(uint4*)&tile[t][c8] = *(const uint4*)(VH + (size_t)(b * T + tt * 64 + t) * DM + h * DH + c8);
  }
  __syncthreads();
#pragma unroll
  for (int it = 0; it < 2; ++it) {
    int chunk = tid + it * 256;
    int d = chunk >> 3, t8 = (chunk & 7) * 8;
    U128 pk;
#pragma unroll
    for (int j = 0; j < 8; ++j) pk.s[j] = tile[t8 + j][d];
    *(uint4*)(VHt + ((size_t)bh * DH + d) * T + tt * 64 + t8) = pk.u;
  }
}

// ---------------- Flash attention + residual ------------------------------------------
// grid 2048: blockIdx -> (bh, q-tile of 64 rows); 4 waves, each 16 q-rows.
__global__ __launch_bounds__(256) void flash_kernel(
    const u16* __restrict__ QH, const u16* __restrict__ KH, const u16* __restrict__ VHt,
    const float* __restrict__ res, float* __restrict__ out) {
  const int qt = blockIdx.x & 31, bh = blockIdx.x >> 5;
  const int b = bh >> 4, h = bh & 15;
  const int tid = threadIdx.x, wave = tid >> 6, lane = tid & 63;
  const int c16 = lane & 15, quad = lane >> 4;
  __shared__ u16 Kl[64][80];       // [krow][d]
  __shared__ u16 Vl[64][80];       // [d][krow]  (transposed V tile)
  __shared__ u16 Pl[4][16][80];    // per-wave P buffer [qrow][krow]
  const int q0 = qt * 64 + wave * 16;
  const u16* qp = QH + (size_t)(b * T + q0 + c16) * DM + h * DH + quad * 8;
  bf16x8 aq0 = *(const bf16x8*)qp;          // A frag: Q[m=c16][k=quad*8+j]
  bf16x8 aq1 = *(const bf16x8*)(qp + 32);
  f32x4 acc[4] = {};
  float mrow[4], lrow[4];
#pragma unroll
  for (int r = 0; r < 4; ++r) { mrow[r] = -1e30f; lrow[r] = 0.f; }
  const float scale = 0.03125f;   // 1/sqrt(d_model)=1/32
  for (int kt = 0; kt < 32; ++kt) {
    __syncthreads();
#pragma unroll
    for (int it = 0; it < 2; ++it) {
      int chunk = tid + it * 256;
      int r = chunk >> 3, c8 = (chunk & 7) * 8;
      *(uint4*)&Kl[r][c8] = *(const uint4*)(KH + (size_t)(b * T + kt * 64 + r) * DM + h * DH + c8);
      *(uint4*)&Vl[r][c8] = *(const uint4*)(VHt + ((size_t)bh * DH + r) * T + kt * 64 + c8);
    }
    __syncthreads();
    // S = Q K^T : 16 x 64, C-layout [row=quad*4+r][col=ns*16+c16]
    f32x4 s[4];
#pragma unroll
    for (int ns = 0; ns < 4; ++ns) {
      bf16x8 bk0 = *(const bf16x8*)&Kl[ns * 16 + c16][quad * 8];
      bf16x8 bk1 = *(const bf16x8*)&Kl[ns * 16 + c16][32 + quad * 8];
      f32x4 t0 = {};
      t0 = __builtin_amdgcn_mfma_f32_16x16x32_bf16(aq0, bk0, t0, 0, 0, 0);
      t0 = __builtin_amdgcn_mfma_f32_16x16x32_bf16(aq1, bk1, t0, 0, 0, 0);
      s[ns] = t0;
    }
    // online softmax: rows of a quad reduce across its 16 lanes
    float mnew[4], alpha[4], rs[4];
#pragma unroll
    for (int r = 0; r < 4; ++r) {
      float mx = fmaxf(fmaxf(s[0][r], s[1][r]), fmaxf(s[2][r], s[3][r])) * scale;
#pragma unroll
      for (int off = 1; off < 16; off <<= 1) mx = fmaxf(mx, __shfl_xor(mx, off, 64));
      mnew[r] = fmaxf(mrow[r], mx);
      rs[r] = 0.f;
    }
#pragma unroll
    for (int ns = 0; ns < 4; ++ns)
#pragma unroll
      for (int r = 0; r < 4; ++r) {
        float pv = __expf(s[ns][r] * scale - mnew[r]);
        rs[r] += pv;
        Pl[wave][quad * 4 + r][ns * 16 + c16] = f2bf(pv);
      }
#pragma unroll
    for (int r = 0; r < 4; ++r) {
      float t2 = rs[r];
#pragma unroll
      for (int off = 1; off < 16; off <<= 1) t2 += __shfl_xor(t2, off, 64);
      alpha[r] = __expf(mrow[r] - mnew[r]);
      lrow[r] = lrow[r] * alpha[r] + t2;
      mrow[r] = mnew[r];
    }
#pragma unroll
    for (int ns = 0; ns < 4; ++ns)
#pragma unroll
      for (int r = 0; r < 4; ++r) acc[ns][r] *= alpha[r];
    // P (C-layout regs) was spilled to LDS; reload in A-layout for PV
    asm volatile("s_waitcnt lgkmcnt(0)" ::: "memory");
    bf16x8 ap0 = *(const bf16x8*)&Pl[wave][c16][quad * 8];
    bf16x8 ap1 = *(const bf16x8*)&Pl[wave][c16][32 + quad * 8];
#pragma unroll
    for (int ns = 0; ns < 4; ++ns) {
      bf16x8 bv0 = *(const bf16x8*)&Vl[ns * 16 + c16][quad * 8];
      bf16x8 bv1 = *(const bf16x8*)&Vl[ns * 16 + c16][32 + quad * 8];
      acc[ns] = __builtin_amdgcn_mfma_f32_16x16x32_bf16(ap0, bv0, acc[ns], 0, 0, 0);
      acc[ns] = __builtin_amdgcn_mfma_f32_16x16x32_bf16(ap1, bv1, acc[ns], 0, 0, 0);
    }
  }
  // epilogue: O/l + residual (fp32)
#pragma unroll
  for (int r = 0; r < 4; ++r) {
    float inv = 1.f / lrow[r];
    size_t rowbase = (size_t)(b * T + q0 + quad * 4 + r) * DM + h * DH;
#pragma unroll
    for (int ns = 0; ns < 4; ++ns) {
      size_t idx = rowbase + ns * 16 + c16;
      out[idx] = acc[ns][r] * inv + res[idx];
    }
  }
}

extern "C" void kernel_launch(void* const* d_in, const int* in_sizes, int n_in,
                              void* d_out, int out_size, void* d_ws, size_t ws_size,
                              hipStream_t stream) {
  const float* q = (const float*)d_in[0];
  const float* k = (const float*)d_in[1];
  const float* v = (const float*)d_in[2];
  const float* WQ = (const float*)d_in[3];
  const float* WK = (const float*)d_in[4];
  const float* WV = (const float*)d_in[5];
  char* ws = (char*)d_ws;
  const size_t WT_B = (size_t)1024 * 1024 * 2;   // one transposed weight, bf16
  const size_t PH_B = (size_t)8192 * 1024 * 2;   // one projected activation, bf16
  u16* WtQ = (u16*)(ws);
  u16* WtK = (u16*)(ws + WT_B);
  u16* WtV = (u16*)(ws + 2 * WT_B);
  u16* QH  = (u16*)(ws + 3 * WT_B);
  u16* KH  = (u16*)(ws + 3 * WT_B + PH_B);
  u16* VH  = (u16*)(ws + 3 * WT_B + 2 * PH_B);
  u16* VHt = (u16*)(ws + 3 * WT_B + 3 * PH_B);

  wt_kernel<<<dim3(16, 16, 3), 256, 0, stream>>>(WQ, WK, WV, WtQ, WtK, WtV);
  gemm_proj<<<dim3(64, 8, 3), 256, 0, stream>>>(q, k, v, WtQ, WtK, WtV, QH, KH, VH);
  vt_kernel<<<2048, 256, 0, stream>>>(VH, VHt);
  flash_kernel<<<2048, 256, 0, stream>>>(QH, KH, VHt, q, (float*)d_out);
}

// Round 2
// 356.178 us; speedup vs baseline: 1.2535x; 1.2535x over previous
//
#include <hip/hip_runtime.h>
#include <cstdint>
#include <cstddef>

typedef __bf16 bf16x8 __attribute__((ext_vector_type(8)));
typedef float f32x4 __attribute__((ext_vector_type(4)));
typedef unsigned short u16;
typedef unsigned int u32;

static constexpr int T = 2048;
static constexpr int DM = 1024;
static constexpr int DH = 64;
// 1/(32*ln2) = log2(e)/32 : folded into W_Q so attention needs only exp2
static constexpr float QSCALE = 0.04508422f;

__device__ __forceinline__ u16 f2bf(float f) {
  u32 u = __builtin_bit_cast(u32, f);
  u += 0x7fffu + ((u >> 16) & 1u);
  return (u16)(u >> 16);
}

// pack two fp32 -> 2 bf16 in one dword, truncation (1 VALU op)
__device__ __forceinline__ u32 pk_trunc(float lo, float hi) {
  return __builtin_amdgcn_perm(__builtin_bit_cast(u32, hi),
                               __builtin_bit_cast(u32, lo), 0x07060302u);
}
// RNE pack (5 ops / pair)
__device__ __forceinline__ u32 pk_rne(float lo, float hi) {
  u32 a = __builtin_bit_cast(u32, lo), b = __builtin_bit_cast(u32, hi);
  a += 0x7fffu + ((a >> 16) & 1u);
  b += 0x7fffu + ((b >> 16) & 1u);
  return __builtin_amdgcn_perm(b, a, 0x07060302u);
}

__device__ __forceinline__ float fexp2(float x) {
#if __has_builtin(__builtin_amdgcn_exp2f)
  return __builtin_amdgcn_exp2f(x);
#else
  return __builtin_exp2f(x);
#endif
}

union U128 { uint4 u; bf16x8 b; u16 s[8]; };

// ---------------- Weight transpose + convert: Wt[n][k] bf16 from W[k][n] fp32 --------
// z==0 (W_Q) additionally scaled by QSCALE (fp32, before rounding).
__global__ __launch_bounds__(256) void wt_kernel(
    const float* __restrict__ W0, const float* __restrict__ W1, const float* __restrict__ W2,
    u16* __restrict__ O0, u16* __restrict__ O1, u16* __restrict__ O2) {
  const float* W = blockIdx.z == 0 ? W0 : blockIdx.z == 1 ? W1 : W2;
  u16* O = blockIdx.z == 0 ? O0 : blockIdx.z == 1 ? O1 : O2;
  const float sc = blockIdx.z == 0 ? QSCALE : 1.0f;
  const int k0 = blockIdx.x * 64, n0 = blockIdx.y * 64;
  __shared__ float tile[64][68];
  const int tid = threadIdx.x;
#pragma unroll
  for (int it = 0; it < 4; ++it) {
    int chunk = tid + it * 256;
    int r = chunk >> 4, c4 = (chunk & 15) * 4;
    *(float4*)&tile[r][c4] = *(const float4*)(W + (size_t)(k0 + r) * DM + n0 + c4);
  }
  __syncthreads();
#pragma unroll
  for (int it = 0; it < 4; ++it) {
    int chunk = tid + it * 256;
    int n = chunk >> 4, k4 = (chunk & 15) * 4;
    ushort4 o;
    o.x = f2bf(tile[k4 + 0][n] * sc);
    o.y = f2bf(tile[k4 + 1][n] * sc);
    o.z = f2bf(tile[k4 + 2][n] * sc);
    o.w = f2bf(tile[k4 + 3][n] * sc);
    *(ushort4*)(O + (size_t)(n0 + n) * DM + k0 + k4) = o;
  }
}

// ---------------- Projection GEMM: O[M,N] bf16 = X[M,K] fp32 * Wt^T, 128x128 tile ----
__global__ __launch_bounds__(256) void gemm_proj(
    const float* __restrict__ Xq, const float* __restrict__ Xk, const float* __restrict__ Xv,
    const u16* __restrict__ Wq, const u16* __restrict__ Wk, const u16* __restrict__ Wv,
    u16* __restrict__ Oq, u16* __restrict__ Ok, u16* __restrict__ Ov) {
  const int z = blockIdx.z;
  const float* X = z == 0 ? Xq : z == 1 ? Xk : Xv;
  const u16* Wt = z == 0 ? Wq : z == 1 ? Wk : Wv;   // [N][K] bf16
  u16* O = z == 0 ? Oq : z == 1 ? Ok : Ov;
  const int m0 = blockIdx.x * 128, n0 = blockIdx.y * 128;
  __shared__ u16 Al[128][40];
  __shared__ u16 Bl[128][40];
  const int tid = threadIdx.x, wave = tid >> 6, lane = tid & 63;
  const int c16 = lane & 15, quad = lane >> 4;
  const int wm = (wave >> 1) * 64, wn = (wave & 1) * 64;
  f32x4 acc[4][4] = {};
  for (int kk = 0; kk < 1024; kk += 32) {
    __syncthreads();
#pragma unroll
    for (int it = 0; it < 2; ++it) {
      int chunk = tid + it * 256;       // 512 chunks of 8 elems
      int r = chunk >> 2, c8 = (chunk & 3) * 8;
      const float* ap = X + (size_t)(m0 + r) * DM + kk + c8;
      float4 a0 = *(const float4*)ap, a1 = *(const float4*)(ap + 4);
      uint4 pk4;
      pk4.x = pk_trunc(a0.x, a0.y);
      pk4.y = pk_trunc(a0.z, a0.w);
      pk4.z = pk_trunc(a1.x, a1.y);
      pk4.w = pk_trunc(a1.z, a1.w);
      *(uint4*)&Al[r][c8] = pk4;
      *(uint4*)&Bl[r][c8] = *(const uint4*)(Wt + (size_t)(n0 + r) * DM + kk + c8);
    }
    __syncthreads();
    bf16x8 af[4], bfr[4];
#pragma unroll
    for (int t = 0; t < 4; ++t) af[t] = *(const bf16x8*)&Al[wm + t * 16 + c16][quad * 8];
#pragma unroll
    for (int t = 0; t < 4; ++t) bfr[t] = *(const bf16x8*)&Bl[wn + t * 16 + c16][quad * 8];
#pragma unroll
    for (int mt = 0; mt < 4; ++mt)
#pragma unroll
      for (int nt = 0; nt < 4; ++nt)
        acc[mt][nt] = __builtin_amdgcn_mfma_f32_16x16x32_bf16(af[mt], bfr[nt], acc[mt][nt], 0, 0, 0);
  }
#pragma unroll
  for (int mt = 0; mt < 4; ++mt)
#pragma unroll
    for (int nt = 0; nt < 4; ++nt)
#pragma unroll
      for (int r = 0; r < 4; ++r) {
        size_t row = m0 + wm + mt * 16 + quad * 4 + r;
        size_t col = n0 + wn + nt * 16 + c16;
        O[row * DM + col] = f2bf(acc[mt][nt][r]);
      }
}

// ---------------- VH transpose: VHt[bh][d][t] = VH[b][t][h*64+d] ----------------------
__global__ __launch_bounds__(256) void vt_kernel(const u16* __restrict__ VH, u16* __restrict__ VHt) {
  const int tt = blockIdx.x & 31, bh = blockIdx.x >> 5;
  const int b = bh >> 4, h = bh & 15;
  __shared__ u16 tile[64][80];
  const int tid = threadIdx.x;
#pragma unroll
  for (int it = 0; it < 2; ++it) {
    int chunk = tid + it * 256;
    int t = chunk >> 3, c8 = (chunk & 7) * 8;
    *(uint4*)&tile[t][c8] = *(const uint4*)(VH + (size_t)(b * T + tt * 64 + t) * DM + h * DH + c8);
  }
  __syncthreads();
#pragma unroll
  for (int it = 0; it < 2; ++it) {
    int chunk = tid + it * 256;
    int d = chunk >> 3, t8 = (chunk & 7) * 8;
    U128 pk;
#pragma unroll
    for (int j = 0; j < 8; ++j) pk.s[j] = tile[t8 + j][d];
    *(uint4*)(VHt + ((size_t)bh * DH + d) * T + tt * 64 + t8) = pk.u;
  }
}

// ---------------- Flash attention + residual, S^T formulation -------------------------
// Sᵀ = K·Qᵀ : C-layout gives each lane 4 consecutive k for ONE q -> packed b64 P writes
// into Pl[q][k], which is exactly the A-fragment layout for P·V.
// Fixed-max softmax: exp2 of pre-scaled scores (QSCALE folded into W_Q); denominator
// accumulated per-lane, reduced across quads once at the end.
__global__ __launch_bounds__(256) void flash_kernel(
    const u16* __restrict__ QH, const u16* __restrict__ KH, const u16* __restrict__ VHt,
    const float* __restrict__ res, float* __restrict__ out) {
  const int qt = blockIdx.x & 31, bh = blockIdx.x >> 5;
  const int b = bh >> 4, h = bh & 15;
  const int tid = threadIdx.x, wave = tid >> 6, lane = tid & 63;
  const int c16 = lane & 15, quad = lane >> 4;
  __shared__ __align__(16) u16 Kl[64][72];      // [k][d]
  __shared__ __align__(16) u16 Vt[64][72];      // [d][k]
  __shared__ __align__(16) u16 Pl[4][16][72];   // per-wave P [q][k]
  __shared__ __align__(16) float Ll[4][16];
  const int q0 = qt * 64 + wave * 16;
  // B-frag for S^T: B[d=quad*8+j][q=c16] = Q[q][d]
  const u16* qp = QH + (size_t)(b * T + q0 + c16) * DM + h * 64 + quad * 8;
  const bf16x8 bq0 = *(const bf16x8*)qp;
  const bf16x8 bq1 = *(const bf16x8*)(qp + 32);
  f32x4 acc[4] = {};          // O[q=quad*4+r][d=nt*16+c16]
  float rs = 0.f;             // partial softmax denominator for q=c16
  const u16* kbase = KH + (size_t)(b * T) * DM + h * 64;
  const u16* vbase = VHt + (size_t)bh * 64 * T;
  const int sr = tid >> 3, sc = (tid & 7) * 8;
  for (int kt = 0; kt < 32; ++kt) {
    __syncthreads();
    {
      const u16* kp = kbase + (size_t)(kt * 64 + sr) * DM + sc;
      const u16* vp = vbase + (size_t)sr * T + kt * 64 + sc;
      uint4 k0 = *(const uint4*)kp;
      uint4 k1 = *(const uint4*)(kp + (size_t)32 * DM);
      uint4 v0 = *(const uint4*)vp;
      uint4 v1 = *(const uint4*)(vp + (size_t)32 * T);
      *(uint4*)&Kl[sr][sc] = k0;
      *(uint4*)&Kl[sr + 32][sc] = k1;
      *(uint4*)&Vt[sr][sc] = v0;
      *(uint4*)&Vt[sr + 32][sc] = v1;
    }
    __syncthreads();
    // S^T tiles: m-tile mt covers k rows mt*16..mt*16+15; inner dim d=64 in 2 chunks
#pragma unroll
    for (int mt = 0; mt < 4; ++mt) {
      const bf16x8 ak0 = *(const bf16x8*)&Kl[mt * 16 + c16][quad * 8];
      const bf16x8 ak1 = *(const bf16x8*)&Kl[mt * 16 + c16][32 + quad * 8];
      f32x4 st = {};
      st = __builtin_amdgcn_mfma_f32_16x16x32_bf16(ak0, bq0, st, 0, 0, 0);
      st = __builtin_amdgcn_mfma_f32_16x16x32_bf16(ak1, bq1, st, 0, 0, 0);
      const float p0 = fexp2(st[0]), p1 = fexp2(st[1]);
      const float p2 = fexp2(st[2]), p3 = fexp2(st[3]);
      rs += (p0 + p1) + (p2 + p3);
      uint2 pw;
      pw.x = pk_rne(p0, p1);
      pw.y = pk_rne(p2, p3);
      *(uint2*)&Pl[wave][c16][mt * 16 + quad * 4] = pw;  // P[q=c16][k=mt*16+quad*4..+3]
    }
    asm volatile("s_waitcnt lgkmcnt(0)" ::: "memory");   // wave-local P visibility
    const bf16x8 ap0 = *(const bf16x8*)&Pl[wave][c16][quad * 8];
    const bf16x8 ap1 = *(const bf16x8*)&Pl[wave][c16][32 + quad * 8];
#pragma unroll
    for (int nt = 0; nt < 4; ++nt) {
      const bf16x8 bv0 = *(const bf16x8*)&Vt[nt * 16 + c16][quad * 8];
      const bf16x8 bv1 = *(const bf16x8*)&Vt[nt * 16 + c16][32 + quad * 8];
      acc[nt] = __builtin_amdgcn_mfma_f32_16x16x32_bf16(ap0, bv0, acc[nt], 0, 0, 0);
      acc[nt] = __builtin_amdgcn_mfma_f32_16x16x32_bf16(ap1, bv1, acc[nt], 0, 0, 0);
    }
  }
  // denominator: reduce over quads (lanes xor 16,32), then transpose q index via LDS
  rs += __shfl_xor(rs, 16, 64);
  rs += __shfl_xor(rs, 32, 64);
  if (quad == 0) Ll[wave][c16] = rs;
  asm volatile("s_waitcnt lgkmcnt(0)" ::: "memory");
  const f32x4 lv = *(const f32x4*)&Ll[wave][quad * 4];
#pragma unroll
  for (int r = 0; r < 4; ++r) {
    const float inv = 1.0f / lv[r];
    const size_t rowbase = (size_t)(b * T + q0 + quad * 4 + r) * DM + h * 64;
#pragma unroll
    for (int nt = 0; nt < 4; ++nt) {
      const size_t idx = rowbase + nt * 16 + c16;
      out[idx] = acc[nt][r] * inv + res[idx];
    }
  }
}

extern "C" void kernel_launch(void* const* d_in, const int* in_sizes, int n_in,
                              void* d_out, int out_size, void* d_ws, size_t ws_size,
                              hipStream_t stream) {
  const float* q = (const float*)d_in[0];
  const float* k = (const float*)d_in[1];
  const float* v = (const float*)d_in[2];
  const float* WQ = (const float*)d_in[3];
  const float* WK = (const float*)d_in[4];
  const float* WV = (const float*)d_in[5];
  char* ws = (char*)d_ws;
  const size_t WT_B = (size_t)1024 * 1024 * 2;
  const size_t PH_B = (size_t)8192 * 1024 * 2;
  u16* WtQ = (u16*)(ws);
  u16* WtK = (u16*)(ws + WT_B);
  u16* WtV = (u16*)(ws + 2 * WT_B);
  u16* QH  = (u16*)(ws + 3 * WT_B);
  u16* KH  = (u16*)(ws + 3 * WT_B + PH_B);
  u16* VH  = (u16*)(ws + 3 * WT_B + 2 * PH_B);
  u16* VHt = (u16*)(ws + 3 * WT_B + 3 * PH_B);

  wt_kernel<<<dim3(16, 16, 3), 256, 0, stream>>>(WQ, WK, WV, WtQ, WtK, WtV);
  gemm_proj<<<dim3(64, 8, 3), 256, 0, stream>>>(q, k, v, WtQ, WtK, WtV, QH, KH, VH);
  vt_kernel<<<2048, 256, 0, stream>>>(VH, VHt);
  flash_kernel<<<2048, 256, 0, stream>>>(QH, KH, VHt, q, (float*)d_out);
}

// Round 3
// 301.070 us; speedup vs baseline: 1.4830x; 1.1830x over previous
//
#include <hip/hip_runtime.h>
#include <cstdint>
#include <cstddef>

typedef __bf16 bf16x8 __attribute__((ext_vector_type(8)));
typedef float f32x4 __attribute__((ext_vector_type(4)));
typedef unsigned short u16;
typedef unsigned int u32;

static constexpr int T = 2048;
static constexpr int DM = 1024;
// 1/(32*ln2) = log2(e)/32 : folded into W_Q so attention needs only exp2
static constexpr float QSCALE = 0.04508422f;

#define GLOBAL_AS __attribute__((address_space(1)))
#define LDS_AS __attribute__((address_space(3)))

__device__ __forceinline__ void gld_lds16(const u16* g, u16* l) {
  __builtin_amdgcn_global_load_lds((const GLOBAL_AS u32*)g, (LDS_AS u32*)l, 16, 0, 0);
}

__device__ __forceinline__ u16 f2bf(float f) {
  u32 u = __builtin_bit_cast(u32, f);
  u += 0x7fffu + ((u >> 16) & 1u);
  return (u16)(u >> 16);
}

// pack two fp32 -> 2 bf16 in one dword: HW pack if available, else truncation
__device__ __forceinline__ u32 pkb(float lo, float hi) {
#if __has_builtin(__builtin_amdgcn_cvt_pk_bf16_f32)
  typedef __bf16 bf16x2 __attribute__((ext_vector_type(2)));
  bf16x2 r = __builtin_amdgcn_cvt_pk_bf16_f32(lo, hi);
  return __builtin_bit_cast(u32, r);
#else
  return __builtin_amdgcn_perm(__builtin_bit_cast(u32, hi),
                               __builtin_bit_cast(u32, lo), 0x07060302u);
#endif
}

__device__ __forceinline__ float fexp2(float x) {
#if __has_builtin(__builtin_amdgcn_exp2f)
  return __builtin_amdgcn_exp2f(x);
#else
  return __builtin_exp2f(x);
#endif
}

// ---------------- X fp32 -> bf16 convert (once) ---------------------------------------
__global__ __launch_bounds__(256) void xcvt(
    const float* __restrict__ q, const float* __restrict__ k, const float* __restrict__ v,
    u16* __restrict__ oq, u16* __restrict__ ok, u16* __restrict__ ov) {
  const float* X = blockIdx.y == 0 ? q : blockIdx.y == 1 ? k : v;
  u16* O = blockIdx.y == 0 ? oq : blockIdx.y == 1 ? ok : ov;
  const size_t i = ((size_t)blockIdx.x * 256 + threadIdx.x) * 8;
  float4 a0 = *(const float4*)(X + i), a1 = *(const float4*)(X + i + 4);
  uint4 p;
  p.x = pkb(a0.x, a0.y); p.y = pkb(a0.z, a0.w);
  p.z = pkb(a1.x, a1.y); p.w = pkb(a1.z, a1.w);
  *(uint4*)(O + i) = p;
}

// ---------------- Weight transpose + convert: Wt[n][k] bf16 from W[k][n] fp32 --------
__global__ __launch_bounds__(256) void wt_kernel(
    const float* __restrict__ W0, const float* __restrict__ W1, const float* __restrict__ W2,
    u16* __restrict__ O0, u16* __restrict__ O1, u16* __restrict__ O2) {
  const float* W = blockIdx.z == 0 ? W0 : blockIdx.z == 1 ? W1 : W2;
  u16* O = blockIdx.z == 0 ? O0 : blockIdx.z == 1 ? O1 : O2;
  const float sc = blockIdx.z == 0 ? QSCALE : 1.0f;
  const int k0 = blockIdx.x * 64, n0 = blockIdx.y * 64;
  __shared__ float tile[64][68];
  const int tid = threadIdx.x;
#pragma unroll
  for (int it = 0; it < 4; ++it) {
    int chunk = tid + it * 256;
    int r = chunk >> 4, c4 = (chunk & 15) * 4;
    *(float4*)&tile[r][c4] = *(const float4*)(W + (size_t)(k0 + r) * DM + n0 + c4);
  }
  __syncthreads();
#pragma unroll
  for (int it = 0; it < 4; ++it) {
    int chunk = tid + it * 256;
    int n = chunk >> 4, k4 = (chunk & 15) * 4;
    ushort4 o;
    o.x = f2bf(tile[k4 + 0][n] * sc);
    o.y = f2bf(tile[k4 + 1][n] * sc);
    o.z = f2bf(tile[k4 + 2][n] * sc);
    o.w = f2bf(tile[k4 + 3][n] * sc);
    *(ushort4*)(O + (size_t)(n0 + n) * DM + k0 + k4) = o;
  }
}

// ---------------- Projection GEMM, m97-style: global_load_lds + XOR swizzle ----------
__global__ __launch_bounds__(256) void gemm_proj(
    const u16* __restrict__ Xq, const u16* __restrict__ Xk, const u16* __restrict__ Xv,
    const u16* __restrict__ Wq, const u16* __restrict__ Wk, const u16* __restrict__ Wv,
    u16* __restrict__ Oq, u16* __restrict__ Ok, u16* __restrict__ Ov) {
  const int z = blockIdx.z;
  const u16* X = z == 0 ? Xq : z == 1 ? Xk : Xv;    // [M][K] bf16
  const u16* Wt = z == 0 ? Wq : z == 1 ? Wk : Wv;   // [N][K] bf16
  u16* O = z == 0 ? Oq : z == 1 ? Ok : Ov;
  const int m0 = blockIdx.x * 128, n0 = blockIdx.y * 128;
  __shared__ u16 Al[128][32];   // unpadded: DMA target; chunk c stored at c^(row&3)
  __shared__ u16 Bl[128][32];
  const int tid = threadIdx.x, w = tid >> 6, lane = tid & 63;
  const int c16 = lane & 15, quad = lane >> 4;
  const int wm = (w >> 1) * 64, wn = (w & 1) * 64;
  const int rL = lane >> 2;                         // 0..15 row within wave group
  const int cL = ((lane & 3) ^ (rL & 3)) * 8;       // swizzled logical col (elems)
  const int sA = (quad ^ (c16 & 3)) * 8;            // frag read col
  f32x4 acc[4][4] = {};
  for (int kk = 0; kk < 1024; kk += 32) {
    __syncthreads();
    {
      const u16* ga = X + (size_t)(m0 + w * 16 + rL) * DM + kk + cL;
      gld_lds16(ga, &Al[w * 16][0]);
      gld_lds16(ga + (size_t)64 * DM, &Al[64 + w * 16][0]);
      const u16* gb = Wt + (size_t)(n0 + w * 16 + rL) * DM + kk + cL;
      gld_lds16(gb, &Bl[w * 16][0]);
      gld_lds16(gb + (size_t)64 * DM, &Bl[64 + w * 16][0]);
    }
    __syncthreads();
    bf16x8 af[4], bfr[4];
#pragma unroll
    for (int t = 0; t < 4; ++t) af[t] = *(const bf16x8*)&Al[wm + t * 16 + c16][sA];
#pragma unroll
    for (int t = 0; t < 4; ++t) bfr[t] = *(const bf16x8*)&Bl[wn + t * 16 + c16][sA];
#pragma unroll
    for (int mt = 0; mt < 4; ++mt)
#pragma unroll
      for (int nt = 0; nt < 4; ++nt)
        acc[mt][nt] = __builtin_amdgcn_mfma_f32_16x16x32_bf16(af[mt], bfr[nt], acc[mt][nt], 0, 0, 0);
  }
#pragma unroll
  for (int mt = 0; mt < 4; ++mt)
#pragma unroll
    for (int nt = 0; nt < 4; ++nt)
#pragma unroll
      for (int r = 0; r < 4; ++r) {
        size_t row = m0 + wm + mt * 16 + quad * 4 + r;
        size_t col = n0 + wn + nt * 16 + c16;
        O[row * DM + col] = f2bf(acc[mt][nt][r]);
      }
}

// ---------------- VH transpose: VHt[bh][d][t] = VH[b][t][h*64+d] ----------------------
__global__ __launch_bounds__(256) void vt_kernel(const u16* __restrict__ VH, u16* __restrict__ VHt) {
  const int tt = blockIdx.x & 31, bh = blockIdx.x >> 5;
  const int b = bh >> 4, h = bh & 15;
  __shared__ u16 tile[64][80];
  const int tid = threadIdx.x;
#pragma unroll
  for (int it = 0; it < 2; ++it) {
    int chunk = tid + it * 256;
    int t = chunk >> 3, c8 = (chunk & 7) * 8;
    *(uint4*)&tile[t][c8] = *(const uint4*)(VH + (size_t)(b * T + tt * 64 + t) * DM + h * 64 + c8);
  }
  __syncthreads();
#pragma unroll
  for (int it = 0; it < 2; ++it) {
    int chunk = tid + it * 256;
    int d = chunk >> 3, t8 = (chunk & 7) * 8;
    union { uint4 u; u16 s[8]; } pk;
#pragma unroll
    for (int j = 0; j < 8; ++j) pk.s[j] = tile[t8 + j][d];
    *(uint4*)(VHt + ((size_t)bh * 64 + d) * T + tt * 64 + t8) = pk.u;
  }
}

// ---------------- Flash attention + residual, S^T form, 64 q-rows per wave ------------
// 512 blocks = 64 bh x 8 q-blocks of 256 rows; 4 waves x 64 q (4 q-tiles of 16).
// K/V tiles DMA'd via global_load_lds into unpadded [64][64] with chunk^=(row&7) swizzle
// (conflict-free b128 frag reads). P round-trip per wave with stride 88 (conflict-free).
__global__ __launch_bounds__(256, 2) void flash_kernel(
    const u16* __restrict__ QH, const u16* __restrict__ KH, const u16* __restrict__ VHt,
    const float* __restrict__ res, float* __restrict__ out) {
  const int blk = blockIdx.x;
  const int x = blk & 7, g = blk >> 3;
  const int bh = x * 8 + (g & 7);          // XCD-grouped: same-bh blocks share an XCD
  const int qb = g >> 3;                   // 0..7
  const int b = bh >> 4, h = bh & 15;
  const int tid = threadIdx.x, w = tid >> 6, lane = tid & 63;
  const int c16 = lane & 15, quad = lane >> 4;
  __shared__ u16 Kl[64][64];               // [k][d], swizzled chunks
  __shared__ u16 Vt[64][64];               // [d][k], swizzled chunks
  __shared__ u16 Pl[4][4][16][88];         // [wave][qi][q][k], stride 88
  __shared__ float Ll[4][4][16];
  const int qbase = qb * 256 + w * 64;
  // Q fragments (resident whole kernel): B[d][q] for 4 q-tiles
  bf16x8 bq[4][2];
#pragma unroll
  for (int qi = 0; qi < 4; ++qi) {
    const u16* qp = QH + (size_t)(b * T + qbase + qi * 16 + c16) * DM + h * 64 + quad * 8;
    bq[qi][0] = *(const bf16x8*)qp;
    bq[qi][1] = *(const bf16x8*)(qp + 32);
  }
  f32x4 acc[4][4] = {};                    // [qi][nt]
  float rs[4] = {0.f, 0.f, 0.f, 0.f};
  const int rk = lane >> 3;                // 0..7
  const int ck8 = ((lane & 7) ^ rk) * 8;   // swizzled global col for DMA
  const u16* kg = KH + (size_t)(b * T) * DM + h * 64 + ck8;
  const u16* vg = VHt + ((size_t)bh * 64 + w * 16 + rk) * T + ck8;
  const int swzq = c16 & 7;
  for (int kt = 0; kt < 32; ++kt) {
    __syncthreads();
    {
      const u16* kg0 = kg + (size_t)(kt * 64 + w * 16 + rk) * DM;
      gld_lds16(kg0, &Kl[w * 16][0]);
      gld_lds16(kg0 + (size_t)8 * DM, &Kl[w * 16 + 8][0]);
      const u16* vg0 = vg + kt * 64;
      gld_lds16(vg0, &Vt[w * 16][0]);
      gld_lds16(vg0 + (size_t)8 * T, &Vt[w * 16 + 8][0]);
    }
    __syncthreads();
    // K fragments: A[k=mt*16+c16][d]
    bf16x8 ak[4][2];
#pragma unroll
    for (int mt = 0; mt < 4; ++mt) {
      const int r = mt * 16 + c16;
      ak[mt][0] = *(const bf16x8*)&Kl[r][(quad ^ swzq) * 8];
      ak[mt][1] = *(const bf16x8*)&Kl[r][((quad + 4) ^ swzq) * 8];
    }
    // Phase A: S^T = K Q^T per q-tile, exp2, pack P
#pragma unroll
    for (int qi = 0; qi < 4; ++qi) {
#pragma unroll
      for (int mt = 0; mt < 4; ++mt) {
        f32x4 st = {};
        st = __builtin_amdgcn_mfma_f32_16x16x32_bf16(ak[mt][0], bq[qi][0], st, 0, 0, 0);
        st = __builtin_amdgcn_mfma_f32_16x16x32_bf16(ak[mt][1], bq[qi][1], st, 0, 0, 0);
        const float p0 = fexp2(st[0]), p1 = fexp2(st[1]);
        const float p2 = fexp2(st[2]), p3 = fexp2(st[3]);
        rs[qi] += (p0 + p1) + (p2 + p3);
        uint2 pw;
        pw.x = pkb(p0, p1);
        pw.y = pkb(p2, p3);
        *(uint2*)&Pl[w][qi][c16][mt * 16 + quad * 4] = pw;
      }
    }
    // V fragments: B[k][d=nt*16+c16] from Vt[d][k]
    bf16x8 bv[4][2];
#pragma unroll
    for (int nt = 0; nt < 4; ++nt) {
      const int r = nt * 16 + c16;
      bv[nt][0] = *(const bf16x8*)&Vt[r][(quad ^ swzq) * 8];
      bv[nt][1] = *(const bf16x8*)&Vt[r][((quad + 4) ^ swzq) * 8];
    }
    asm volatile("s_waitcnt lgkmcnt(0)" ::: "memory");  // P writes visible (same wave)
    // Phase B: O += P V
#pragma unroll
    for (int qi = 0; qi < 4; ++qi) {
      const bf16x8 ap0 = *(const bf16x8*)&Pl[w][qi][c16][quad * 8];
      const bf16x8 ap1 = *(const bf16x8*)&Pl[w][qi][c16][32 + quad * 8];
#pragma unroll
      for (int nt = 0; nt < 4; ++nt) {
        acc[qi][nt] = __builtin_amdgcn_mfma_f32_16x16x32_bf16(ap0, bv[nt][0], acc[qi][nt], 0, 0, 0);
        acc[qi][nt] = __builtin_amdgcn_mfma_f32_16x16x32_bf16(ap1, bv[nt][1], acc[qi][nt], 0, 0, 0);
      }
    }
  }
  // softmax denominators: reduce over quads, broadcast via LDS
#pragma unroll
  for (int qi = 0; qi < 4; ++qi) {
    float t = rs[qi];
    t += __shfl_xor(t, 16, 64);
    t += __shfl_xor(t, 32, 64);
    if (quad == 0) Ll[w][qi][c16] = t;
  }
  asm volatile("s_waitcnt lgkmcnt(0)" ::: "memory");
#pragma unroll
  for (int qi = 0; qi < 4; ++qi) {
    const f32x4 lv = *(const f32x4*)&Ll[w][qi][quad * 4];
#pragma unroll
    for (int r = 0; r < 4; ++r) {
      const float inv = 1.0f / lv[r];
      const size_t rowbase = (size_t)(b * T + qbase + qi * 16 + quad * 4 + r) * DM + h * 64;
#pragma unroll
      for (int nt = 0; nt < 4; ++nt) {
        const size_t idx = rowbase + nt * 16 + c16;
        out[idx] = acc[qi][nt][r] * inv + res[idx];
      }
    }
  }
}

extern "C" void kernel_launch(void* const* d_in, const int* in_sizes, int n_in,
                              void* d_out, int out_size, void* d_ws, size_t ws_size,
                              hipStream_t stream) {
  const float* q = (const float*)d_in[0];
  const float* k = (const float*)d_in[1];
  const float* v = (const float*)d_in[2];
  const float* WQ = (const float*)d_in[3];
  const float* WK = (const float*)d_in[4];
  const float* WV = (const float*)d_in[5];
  char* ws = (char*)d_ws;
  const size_t PH = (size_t)8192 * 1024 * 2;   // bf16 activation buffer bytes
  const size_t WT = (size_t)1024 * 1024 * 2;
  // d_out (33.5 MB fp32) doubles as scratch for 2 of the 3 bf16 X tensors; it is
  // fully rewritten by flash at the end. ws stays at 73.4 MB (round-2 footprint).
  u16* XqB = (u16*)d_out;
  u16* XkB = (u16*)d_out + (size_t)8192 * 1024;
  u16* XvB = (u16*)(ws);                        // slot 0, later reused for VHt
  u16* WtQ = (u16*)(ws + PH);
  u16* WtK = (u16*)(ws + PH + WT);
  u16* WtV = (u16*)(ws + PH + 2 * WT);
  u16* QH  = (u16*)(ws + PH + 3 * WT);
  u16* KH  = (u16*)(ws + 2 * PH + 3 * WT);
  u16* VH  = (u16*)(ws + 3 * PH + 3 * WT);
  u16* VHt = XvB;                               // XvB dead after gemm_proj

  xcvt<<<dim3(4096, 3), 256, 0, stream>>>(q, k, v, XqB, XkB, XvB);
  wt_kernel<<<dim3(16, 16, 3), 256, 0, stream>>>(WQ, WK, WV, WtQ, WtK, WtV);
  gemm_proj<<<dim3(64, 8, 3), 256, 0, stream>>>(XqB, XkB, XvB, WtQ, WtK, WtV, QH, KH, VH);
  vt_kernel<<<2048, 256, 0, stream>>>(VH, VHt);
  flash_kernel<<<512, 256, 0, stream>>>(QH, KH, VHt, q, (float*)d_out);
}